// Round 4
// baseline (647.014 us; speedup 1.0000x reference)
//
#include <hip/hip_runtime.h>
#include <stdint.h>
#include <stddef.h>

// C[4096,11008] = X[4096,4096] @ W^T, W = int4 group-128 dequant.
// R7: R6's fragment-pipelined single-barrier schedule FAILED (absmax 6.9) from
// a cross-wave race: WAIT_VM4 at even-phase TOPS only covers the waiting
// wave's own gload_lds; the ds_reads consume rows staged by OTHER waves, whose
// loads need not have landed (barrier orders execution, not in-flight vmem).
// Fix: counted wait moved to END of odd phases, BEFORE the barrier:
//   odd  = [RD cur-sec MH1 | STAGE4 | 16 MFMA | vmcnt(4) | bar]
//   even = [RD next-sec frags | 16 MFMA | bar]
// Invariant restored: {each wave waits own loads} -> barrier -> {reads}.
// Ledger (8 outstanding at each odd wait, retire oldest 4): prologue-h1@ph1,
// G1@ph3, G2@ph5, G3@ph7, G4@next-ph1 -- each group ~2 phases in flight,
// never drained to 0. Fragment regs af/bf double-buffered; MFMA overlaps the
// next phase's LDS drain (compiler emits partial lgkmcnt).

#define M_TOK 4096
#define K_IN  4096
#define N_OUT 11008
#define NGRP  32

#define MTI 16            // 4096/256
#define NTI 43            // 11008/256
#define TILES (MTI * NTI) // 688 = 8*86

#define BH_OFF ((size_t)M_TOK * K_IN * 2)   // Ah: 32 MiB, then Bh: 86 MiB

typedef _Float16 h8v __attribute__((ext_vector_type(8)));
typedef float    f4v __attribute__((ext_vector_type(4)));

__device__ __forceinline__ void gload16(const void* g, void* l) {
  __builtin_amdgcn_global_load_lds(
      (__attribute__((address_space(1))) void*)(g),
      (__attribute__((address_space(3))) void*)(l),
      16, 0, 0);
}

#define MEMFENCE asm volatile("" ::: "memory")
__device__ __forceinline__ void bar() {
  MEMFENCE;
  __builtin_amdgcn_s_barrier();
  MEMFENCE;
}
#define WAIT_VM4 asm volatile("s_waitcnt vmcnt(4)" ::: "memory")

// ---- prepass 1: X f32 -> f16, natural order ----
__global__ __launch_bounds__(256) void cvt_x_kernel(const float* __restrict__ x,
                                                    _Float16* __restrict__ xh) {
  size_t t = (size_t)blockIdx.x * 256 + threadIdx.x;
  const float4* s = (const float4*)x + t * 2;
  float4 a = s[0], b = s[1];
  h8v o;
  o[0] = (_Float16)a.x; o[1] = (_Float16)a.y; o[2] = (_Float16)a.z; o[3] = (_Float16)a.w;
  o[4] = (_Float16)b.x; o[5] = (_Float16)b.y; o[6] = (_Float16)b.z; o[7] = (_Float16)b.w;
  ((h8v*)xh)[t] = o;
}

// ---- prepass 2: full dequant W -> f16 [OUT][IN], natural order ----
// w[k=2i] = (sext4(lo) - z) * s = s*(lo^8) + c,  c = -s*(8+z)
__global__ __launch_bounds__(256) void dequant_w_kernel(const int* __restrict__ wp,
                                                        const float* __restrict__ ws,
                                                        const int* __restrict__ wz,
                                                        _Float16* __restrict__ bh) {
  size_t tg = (size_t)blockIdx.x * 256 + threadIdx.x;
  int j   = (int)(tg & 127);   // 128 threads per row, 16 ints each
  int row = (int)(tg >> 7);
  int g = j >> 2;              // 32 weights per thread, group = 128
  float s = ws[(size_t)row * NGRP + g];
  float c = -s * (8.0f + (float)wz[(size_t)row * NGRP + g]);
  const int4* src = (const int4*)(wp + (size_t)row * 2048 + j * 16);
  _Float16* dst = bh + (size_t)row * 4096 + j * 32;
#pragma unroll
  for (int b = 0; b < 4; ++b) {
    int4 v = src[b];
    int q[4] = {v.x, v.y, v.z, v.w};
    h8v o;
#pragma unroll
    for (int i = 0; i < 4; ++i) {
      int lo = (q[i] & 15) ^ 8;
      int hi = ((q[i] >> 4) & 15) ^ 8;
      o[2 * i]     = (_Float16)(s * (float)lo + c);
      o[2 * i + 1] = (_Float16)(s * (float)hi + c);
    }
    ((h8v*)dst)[b] = o;
  }
}

// ---- GEMM: 256x256 tile, BK=64, 8 waves (2M x 4N), pipelined 8-phase ----
// LDS per buffer: A 32KB (2 K-half sections of 16KB) + B 32KB. 2 buffers = 128KB.
// byte(row,kchunk) = sec(kchunk>>2)*16384 + (row*4 + (kchunk&3)^((row>>1)&3))*16
__global__ __launch_bounds__(512, 2) void gemm_kernel(
    const _Float16* __restrict__ Ah,
    const _Float16* __restrict__ Bh,
    float* __restrict__ C) {
  __shared__ __align__(128) char smem[131072];

  const int bid = blockIdx.x;
  // XCD swizzle, bijective (688 = 8*86): each XCD owns 2 full m-rows of tiles
  const int swz = (bid & 7) * 86 + (bid >> 3);
  const int mt = swz / NTI;
  const int nt = swz - mt * NTI;
  const int m0 = mt * 256;
  const int n0 = nt * 256;

  const int tid  = threadIdx.x;
  const int lane = tid & 63;
  const int wid  = tid >> 6;
  const int wm   = wid >> 2;   // 0..1
  const int wn   = wid & 3;    // 0..3
  const int lrow = lane & 15;
  const int quad = lane >> 4;

  // staging: thread covers rows r0, r0+16 of the tile, one 16B kchunk each.
  // pre-swizzled global kchunk so linear gload_lds dest realizes the LDS swizzle.
  const int r0 = wid * 32 + (lane >> 2);             // 0..255 (j=0), +16 (j=1)
  const int kc = (lane & 3) ^ ((lane >> 3) & 3);     // slot ^ f(row), f = (row>>1)&3
  const size_t gA0 = (size_t)(m0 + r0) * K_IN + kc * 8;
  const size_t gB0 = (size_t)(n0 + r0) * K_IN + kc * 8;
  const int ldsl = wid * 2048;                       // + j*1024, wave-uniform

  // fragment read offsets (within a section): slot = quad ^ ((row>>1)&3)
  const int su   = quad ^ ((lrow >> 1) & 3);
  const int aoff = ((wm * 128 + lrow) * 4 + su) * 16;
  const int boff = 32768 + ((wn * 64 + lrow) * 4 + su) * 16;

  f4v acc[8][4];
#pragma unroll
  for (int i = 0; i < 8; ++i)
#pragma unroll
    for (int j = 0; j < 4; ++j) acc[i][j] = (f4v){0.f, 0.f, 0.f, 0.f};

  h8v af_a[4], af_b[4], bf_a[4], bf_b[4];

// stage both A and B halves of (tile KT, k-half KH) -> buffer NXT (4 loads)
#define STAGE4(NXT, KT, KH)                                                    \
  { const _Float16* gA_ = Ah + gA0 + (size_t)(KT) * 64 + (KH) * 32;            \
    const _Float16* gB_ = Bh + gB0 + (size_t)(KT) * 64 + (KH) * 32;            \
    char* lA_ = smem + (NXT) * 65536 + (KH) * 16384 + ldsl;                    \
    gload16(gA_, lA_);                                                         \
    gload16(gA_ + 16 * K_IN, lA_ + 1024);                                      \
    gload16(gB_, lA_ + 32768);                                                 \
    gload16(gB_ + 16 * K_IN, lA_ + 32768 + 1024); }

#define RD_AF(DST, BUF, SEC, MH)                                               \
  { const char* s_ = smem + (BUF) * 65536 + (SEC) * 16384;                     \
    _Pragma("unroll")                                                          \
    for (int i_ = 0; i_ < 4; ++i_)                                             \
      DST[i_] = *(const h8v*)(s_ + aoff + (MH) * 4096 + i_ * 1024); }

#define RD_BF(DST, BUF, SEC)                                                   \
  { const char* s_ = smem + (BUF) * 65536 + (SEC) * 16384;                     \
    _Pragma("unroll")                                                          \
    for (int i_ = 0; i_ < 4; ++i_)                                             \
      DST[i_] = *(const h8v*)(s_ + boff + i_ * 1024); }

#define MFMA16(AF, BF, MH)                                                     \
  { __builtin_amdgcn_s_setprio(1);                                             \
    _Pragma("unroll")                                                          \
    for (int mi_ = 0; mi_ < 4; ++mi_)                                          \
      _Pragma("unroll")                                                        \
      for (int nf_ = 0; nf_ < 4; ++nf_)                                        \
        acc[(MH) * 4 + mi_][nf_] = __builtin_amdgcn_mfma_f32_16x16x32_f16(     \
            AF[mi_], BF[nf_], acc[(MH) * 4 + mi_][nf_], 0, 0, 0);              \
    __builtin_amdgcn_s_setprio(0); }

  // prologue: tile 0 both halves -> buf0; retire h0 group (all waves) -> bar;
  // pre-read first fragments.
  STAGE4(0, 0, 0);
  STAGE4(0, 0, 1);
  WAIT_VM4;
  bar();
  RD_AF(af_a, 0, 0, 0);
  RD_BF(bf_a, 0, 0);

  // iteration: compute tile t (buf0, ph1-4) and t+1 (buf1, ph5-8);
  // stage t+1 -> buf1 (G1@ph1 h0, G2@ph3 h1), t+2 -> buf0 (G3@ph5, G4@ph7).
  // Odd phases end [vmcnt(4); bar]: retire the group consumed by the NEXT
  // even phase's reads, on ALL waves, before any wave crosses the barrier.
  for (int t = 0; t < 64; t += 2) {
    const int t1 = t + 1;
    const int t2 = (t + 2 < 64) ? t + 2 : 63;  // tail: dummy restage, dead
    // ph1: compute buf0 s0 MH0; pre-read buf0 s0 MH1; retire prev group
    RD_AF(af_b, 0, 0, 1); STAGE4(1, t1, 0); MFMA16(af_a, bf_a, 0); WAIT_VM4; bar();
    // ph2: compute buf0 s0 MH1; pre-read buf0 s1 (af MH0 + bf)
    RD_AF(af_a, 0, 1, 0); RD_BF(bf_b, 0, 1); MFMA16(af_b, bf_a, 1); bar();
    // ph3: compute buf0 s1 MH0; pre-read buf0 s1 MH1; retire G1
    RD_AF(af_b, 0, 1, 1); STAGE4(1, t1, 1); MFMA16(af_a, bf_b, 0); WAIT_VM4; bar();
    // ph4: compute buf0 s1 MH1; pre-read buf1 s0 (af MH0 + bf)
    RD_AF(af_a, 1, 0, 0); RD_BF(bf_a, 1, 0); MFMA16(af_b, bf_b, 1); bar();
    // ph5: compute buf1 s0 MH0; pre-read buf1 s0 MH1; retire G2
    RD_AF(af_b, 1, 0, 1); STAGE4(0, t2, 0); MFMA16(af_a, bf_a, 0); WAIT_VM4; bar();
    // ph6: compute buf1 s0 MH1; pre-read buf1 s1 (af MH0 + bf)
    RD_AF(af_a, 1, 1, 0); RD_BF(bf_b, 1, 1); MFMA16(af_b, bf_a, 1); bar();
    // ph7: compute buf1 s1 MH0; pre-read buf1 s1 MH1; retire G3
    RD_AF(af_b, 1, 1, 1); STAGE4(0, t2, 1); MFMA16(af_a, bf_b, 0); WAIT_VM4; bar();
    // ph8: compute buf1 s1 MH1; pre-read buf0 s0 (af MH0 + bf) for next iter
    RD_AF(af_a, 0, 0, 0); RD_BF(bf_a, 0, 0); MFMA16(af_b, bf_b, 1); bar();
  }

  // epilogue: C/D layout col = lane&15 (n), row = quad*4 + reg (m)
#pragma unroll
  for (int mf = 0; mf < 8; ++mf) {
#pragma unroll
    for (int rr = 0; rr < 4; ++rr) {
      int m = m0 + wm * 128 + mf * 16 + quad * 4 + rr;
      float* crow = C + (size_t)m * N_OUT + n0 + wn * 64 + lrow;
#pragma unroll
      for (int nf = 0; nf < 4; ++nf) crow[nf * 16] = acc[mf][nf][rr];
    }
  }
#undef MFMA16
#undef RD_BF
#undef RD_AF
#undef STAGE4
}

extern "C" void kernel_launch(void* const* d_in, const int* in_sizes, int n_in,
                              void* d_out, int out_size, void* d_ws, size_t ws_size,
                              hipStream_t stream) {
  const float* x   = (const float*)d_in[0];
  const int*   wp  = (const int*)d_in[1];
  const float* wsc = (const float*)d_in[2];
  const int*   wz  = (const int*)d_in[3];

  _Float16* Ah = (_Float16*)d_ws;
  _Float16* Bh = (_Float16*)((char*)d_ws + BH_OFF);

  cvt_x_kernel<<<(M_TOK * (size_t)K_IN) / (8 * 256), 256, 0, stream>>>(x, Ah);
  dequant_w_kernel<<<((size_t)N_OUT * 128) / 256, 256, 0, stream>>>(wp, wsc, wz, Bh);
  gemm_kernel<<<TILES, 512, 0, stream>>>(Ah, Bh, (float*)d_out);
}

// Round 5
// 645.556 us; speedup vs baseline: 1.0023x; 1.0023x over previous
//
#include <hip/hip_runtime.h>
#include <stdint.h>
#include <stddef.h>

// C[4096,11008] = X[4096,4096] @ W^T, W = int4 group-128 dequant.
// R8: R7 == R5 (44.6% MfmaUtil) despite pipelining => root cause found: the
// asm("" ::: "memory") wrapped around every s_barrier forces the compiler to
// conservatively drain vmcnt(0)+lgkmcnt(0) (a memory-clobbering asm may touch
// the LDS that in-flight gload_lds writes / ds_reads read). So ALL prior
// "counted vmcnt" schedules actually ran drain-to-zero per phase -- the
// documented 8ph-with-drain0 == 1ph regime (m218: counted-vs-drain0 is the
// +38-73% lever). Cycle check: serialized LDS-drain ~2300cy + MFMA ~2480cy =
// ~4780cy/K-tile == measured ~5200.
// Fix: m201 discipline verbatim -- NO memory clobbers anywhere. Raw
// s_barrier; bare "s_waitcnt lgkmcnt(0)" + sched_barrier(0) (rule #18) after
// the pre-MFMA barrier; bare counted "s_waitcnt vmcnt(4)" before the closing
// barrier of even phases. Phase = [ds_read frags | stage | bar | lgkm0+SB0 |
// setprio(1) 16xMFMA setprio(0) | vmcnt(4)? | bar].
// Ledger (per wave, 4-load groups at ph1/3/5/7; vmcnt(4) at ph2/4/6/8):
// outstanding always 8->4, never 0; retired group is published by that
// phase's closing barrier and read by the NEXT odd phase (wait->bar->read on
// all waves, the R6 lesson). WAR: stage targets sections last read >=3
// barriers earlier, and those reads complete at their phase's lgkm0.

#define M_TOK 4096
#define K_IN  4096
#define N_OUT 11008
#define NGRP  32

#define MTI 16            // 4096/256
#define NTI 43            // 11008/256
#define TILES (MTI * NTI) // 688 = 8*86

#define BH_OFF ((size_t)M_TOK * K_IN * 2)   // Ah: 32 MiB, then Bh: 86 MiB

typedef _Float16 h8v __attribute__((ext_vector_type(8)));
typedef float    f4v __attribute__((ext_vector_type(4)));

__device__ __forceinline__ void gload16(const void* g, void* l) {
  __builtin_amdgcn_global_load_lds(
      (__attribute__((address_space(1))) void*)(g),
      (__attribute__((address_space(3))) void*)(l),
      16, 0, 0);
}

// NO memory clobbers: counted waits must not force compiler-inserted drains.
#define WAIT_VM4 asm volatile("s_waitcnt vmcnt(4)")
#define LGKM0_SB0                                                              \
  { asm volatile("s_waitcnt lgkmcnt(0)");                                      \
    __builtin_amdgcn_sched_barrier(0); }
#define BAR __builtin_amdgcn_s_barrier()

// ---- prepass 1: X f32 -> f16, natural order ----
__global__ __launch_bounds__(256) void cvt_x_kernel(const float* __restrict__ x,
                                                    _Float16* __restrict__ xh) {
  size_t t = (size_t)blockIdx.x * 256 + threadIdx.x;
  const float4* s = (const float4*)x + t * 2;
  float4 a = s[0], b = s[1];
  h8v o;
  o[0] = (_Float16)a.x; o[1] = (_Float16)a.y; o[2] = (_Float16)a.z; o[3] = (_Float16)a.w;
  o[4] = (_Float16)b.x; o[5] = (_Float16)b.y; o[6] = (_Float16)b.z; o[7] = (_Float16)b.w;
  ((h8v*)xh)[t] = o;
}

// ---- prepass 2: full dequant W -> f16 [OUT][IN], natural order ----
// w[k=2i] = (sext4(lo) - z) * s = s*(lo^8) + c,  c = -s*(8+z)
__global__ __launch_bounds__(256) void dequant_w_kernel(const int* __restrict__ wp,
                                                        const float* __restrict__ ws,
                                                        const int* __restrict__ wz,
                                                        _Float16* __restrict__ bh) {
  size_t tg = (size_t)blockIdx.x * 256 + threadIdx.x;
  int j   = (int)(tg & 127);   // 128 threads per row, 16 ints each
  int row = (int)(tg >> 7);
  int g = j >> 2;              // 32 weights per thread, group = 128
  float s = ws[(size_t)row * NGRP + g];
  float c = -s * (8.0f + (float)wz[(size_t)row * NGRP + g]);
  const int4* src = (const int4*)(wp + (size_t)row * 2048 + j * 16);
  _Float16* dst = bh + (size_t)row * 4096 + j * 32;
#pragma unroll
  for (int b = 0; b < 4; ++b) {
    int4 v = src[b];
    int q[4] = {v.x, v.y, v.z, v.w};
    h8v o;
#pragma unroll
    for (int i = 0; i < 4; ++i) {
      int lo = (q[i] & 15) ^ 8;
      int hi = ((q[i] >> 4) & 15) ^ 8;
      o[2 * i]     = (_Float16)(s * (float)lo + c);
      o[2 * i + 1] = (_Float16)(s * (float)hi + c);
    }
    ((h8v*)dst)[b] = o;
  }
}

// ---- GEMM: 256x256 tile, BK=64, 8 waves (2M x 4N), 8-phase counted-vmcnt ----
// LDS per buffer: A 32KB (2 K-half sections of 16KB) + B 32KB. 2 buffers = 128KB.
// byte(row,kchunk) = sec(kchunk>>2)*16384 + (row*4 + (kchunk&3)^((row>>1)&3))*16
__global__ __launch_bounds__(512, 2) void gemm_kernel(
    const _Float16* __restrict__ Ah,
    const _Float16* __restrict__ Bh,
    float* __restrict__ C) {
  __shared__ __align__(128) char smem[131072];

  const int bid = blockIdx.x;
  // XCD swizzle, bijective (688 = 8*86): each XCD owns 2 full m-rows of tiles
  const int swz = (bid & 7) * 86 + (bid >> 3);
  const int mt = swz / NTI;
  const int nt = swz - mt * NTI;
  const int m0 = mt * 256;
  const int n0 = nt * 256;

  const int tid  = threadIdx.x;
  const int lane = tid & 63;
  const int wid  = tid >> 6;
  const int wm   = wid >> 2;   // 0..1
  const int wn   = wid & 3;    // 0..3
  const int lrow = lane & 15;
  const int quad = lane >> 4;

  // staging: thread covers rows r0, r0+16 of the tile, one 16B kchunk each.
  // pre-swizzled global kchunk so linear gload_lds dest realizes the LDS swizzle.
  const int r0 = wid * 32 + (lane >> 2);             // 0..255 (j=0), +16 (j=1)
  const int kc = (lane & 3) ^ ((lane >> 3) & 3);     // slot ^ f(row), f = (row>>1)&3
  const size_t gA0 = (size_t)(m0 + r0) * K_IN + kc * 8;
  const size_t gB0 = (size_t)(n0 + r0) * K_IN + kc * 8;
  const int ldsl = wid * 2048;                       // + j*1024, wave-uniform

  // fragment read offsets (within a section): slot = quad ^ ((row>>1)&3)
  const int su   = quad ^ ((lrow >> 1) & 3);
  const int aoff = ((wm * 128 + lrow) * 4 + su) * 16;
  const int boff = 32768 + ((wn * 64 + lrow) * 4 + su) * 16;

  f4v acc[8][4];
#pragma unroll
  for (int i = 0; i < 8; ++i)
#pragma unroll
    for (int j = 0; j < 4; ++j) acc[i][j] = (f4v){0.f, 0.f, 0.f, 0.f};

  h8v af[4], bf[4];

// stage both A and B halves of (tile KT, k-half KH) -> buffer NXT (4 loads)
#define STAGE4(NXT, KT, KH)                                                    \
  { const _Float16* gA_ = Ah + gA0 + (size_t)(KT) * 64 + (KH) * 32;            \
    const _Float16* gB_ = Bh + gB0 + (size_t)(KT) * 64 + (KH) * 32;            \
    char* lA_ = smem + (NXT) * 65536 + (KH) * 16384 + ldsl;                    \
    gload16(gA_, lA_);                                                         \
    gload16(gA_ + 16 * K_IN, lA_ + 1024);                                      \
    gload16(gB_, lA_ + 32768);                                                 \
    gload16(gB_ + 16 * K_IN, lA_ + 32768 + 1024); }

// one phase (m201 shape): reads+stage BEFORE barrier, lgkm0+SB0 after,
// prioritized MFMA, counted vmcnt at even phases, closing barrier.
#define PHASE(CUR, SEC, MH, DO_STAGE, DO_VM)                                   \
  {                                                                            \
    const char* sec_ = smem + (CUR) * 65536 + (SEC) * 16384;                   \
    if ((MH) == 0) {                                                           \
      _Pragma("unroll")                                                        \
      for (int nf_ = 0; nf_ < 4; ++nf_)                                        \
        bf[nf_] = *(const h8v*)(sec_ + boff + nf_ * 1024);                     \
    }                                                                          \
    _Pragma("unroll")                                                          \
    for (int i_ = 0; i_ < 4; ++i_)                                             \
      af[i_] = *(const h8v*)(sec_ + aoff + (MH) * 4096 + i_ * 1024);           \
    DO_STAGE;                                                                  \
    BAR;                                                                       \
    LGKM0_SB0;                                                                 \
    __builtin_amdgcn_s_setprio(1);                                             \
    _Pragma("unroll")                                                          \
    for (int mi_ = 0; mi_ < 4; ++mi_)                                          \
      _Pragma("unroll")                                                        \
      for (int nf_ = 0; nf_ < 4; ++nf_)                                        \
        acc[(MH) * 4 + mi_][nf_] = __builtin_amdgcn_mfma_f32_16x16x32_f16(     \
            af[mi_], bf[nf_], acc[(MH) * 4 + mi_][nf_], 0, 0, 0);              \
    __builtin_amdgcn_s_setprio(0);                                             \
    if (DO_VM) { WAIT_VM4; }                                                   \
    BAR;                                                                       \
  }

  // prologue: tile 0 both halves -> buf0 (P0=h0, P1=h1); vmcnt(4) retires P0
  // on all waves; barrier publishes it for ph1's reads.
  STAGE4(0, 0, 0);
  STAGE4(0, 0, 1);
  WAIT_VM4;
  BAR;

  // Stages: G1@ph1 (t+1 h0 -> buf1), G2@ph3 (t+1 h1), G3@ph5 (t+2 h0 -> buf0),
  // G4@ph7 (t+2 h1). vmcnt(4)@ph2/4/6/8 retires P1/G1/G2/G3 resp., each read
  // by the following odd phase. Outstanding 8->4, never 0.
  for (int t = 0; t < 64; t += 2) {
    const int t1 = t + 1;
    const int t2 = (t + 2 < 64) ? t + 2 : 63;  // tail: dummy restage, dead
    PHASE(0, 0, 0, STAGE4(1, t1, 0), 0)  // ph1
    PHASE(0, 0, 1, {},                1)  // ph2
    PHASE(0, 1, 0, STAGE4(1, t1, 1), 0)  // ph3
    PHASE(0, 1, 1, {},                1)  // ph4
    PHASE(1, 0, 0, STAGE4(0, t2, 0), 0)  // ph5
    PHASE(1, 0, 1, {},                1)  // ph6
    PHASE(1, 1, 0, STAGE4(0, t2, 1), 0)  // ph7
    PHASE(1, 1, 1, {},                1)  // ph8
  }

  // epilogue: C/D layout col = lane&15 (n), row = quad*4 + reg (m)
#pragma unroll
  for (int mf = 0; mf < 8; ++mf) {
#pragma unroll
    for (int rr = 0; rr < 4; ++rr) {
      int m = m0 + wm * 128 + mf * 16 + quad * 4 + rr;
      float* crow = C + (size_t)m * N_OUT + n0 + wn * 64 + lrow;
#pragma unroll
      for (int nf = 0; nf < 4; ++nf) crow[nf * 16] = acc[mf][nf][rr];
    }
  }
#undef PHASE
#undef STAGE4
}

extern "C" void kernel_launch(void* const* d_in, const int* in_sizes, int n_in,
                              void* d_out, int out_size, void* d_ws, size_t ws_size,
                              hipStream_t stream) {
  const float* x   = (const float*)d_in[0];
  const int*   wp  = (const int*)d_in[1];
  const float* wsc = (const float*)d_in[2];
  const int*   wz  = (const int*)d_in[3];

  _Float16* Ah = (_Float16*)d_ws;
  _Float16* Bh = (_Float16*)((char*)d_ws + BH_OFF);

  cvt_x_kernel<<<(M_TOK * (size_t)K_IN) / (8 * 256), 256, 0, stream>>>(x, Ah);
  dequant_w_kernel<<<((size_t)N_OUT * 128) / 256, 256, 0, stream>>>(wp, wsc, wz, Bh);
  gemm_kernel<<<TILES, 512, 0, stream>>>(Ah, Bh, (float*)d_out);
}

// Round 6
// 643.122 us; speedup vs baseline: 1.0061x; 1.0038x over previous
//
#include <hip/hip_runtime.h>
#include <stdint.h>
#include <stddef.h>

// C[4096,11008] = X[4096,4096] @ W^T, W = int4 group-128 dequant.
// R9: completing the 2x2. R5/R7/R8 all ~366-388us, MfmaUtil 43-46:
//   clobber-drain x serial-reads (R5) = clobber x pipelined (R7) =
//   clean-waits x serial (R8). Serial-reads structure forces each wave's own
//   lgkm0 drain before its own MFMA (LDS 576cy + MFMA 310cy add -> 1353cy
//   phases); the clobbered barriers in R7 forced the same drain despite
//   pipelining. THIS round = pipelined fragments + clean waits:
//   odd  = [RD cur-sec MH1 -> alt regs | STAGE4 | MFMA on prev regs |
//           vmcnt(4) | bar]
//   even = [RD next-sec frags -> alt regs | MFMA on prev regs | bar]
// No memory clobbers anywhere; no manual lgkmcnt: compiler's register
// dependence tracking emits partial lgkm waits, so this phase's ds_reads
// drain UNDER the MFMA cluster. Correctness identical to R7 (passed):
// every fresh-section read sits after {all-waves vmcnt(4) -> barrier}
// (G1:ph1->wait ph3->read ph4; G2:ph3->ph5->ph6; G3:ph5->ph7->ph8;
// G4:ph7->next ph1->ph2); WAR: section overwrites >=3 barriers after last
// read, which completed at the consuming MFMA's lgkm wait. Outstanding
// vmem per wave: 8->4 at each odd-phase wait, never drained to 0.

#define M_TOK 4096
#define K_IN  4096
#define N_OUT 11008
#define NGRP  32

#define MTI 16            // 4096/256
#define NTI 43            // 11008/256
#define TILES (MTI * NTI) // 688 = 8*86

#define BH_OFF ((size_t)M_TOK * K_IN * 2)   // Ah: 32 MiB, then Bh: 86 MiB

typedef _Float16 h8v __attribute__((ext_vector_type(8)));
typedef float    f4v __attribute__((ext_vector_type(4)));

__device__ __forceinline__ void gload16(const void* g, void* l) {
  __builtin_amdgcn_global_load_lds(
      (__attribute__((address_space(1))) void*)(g),
      (__attribute__((address_space(3))) void*)(l),
      16, 0, 0);
}

// Clean counted waits: NO memory clobbers (they force vmcnt0/lgkm0 drains).
#define WAIT_VM4 asm volatile("s_waitcnt vmcnt(4)")
#define BAR __builtin_amdgcn_s_barrier()

// ---- prepass 1: X f32 -> f16, natural order ----
__global__ __launch_bounds__(256) void cvt_x_kernel(const float* __restrict__ x,
                                                    _Float16* __restrict__ xh) {
  size_t t = (size_t)blockIdx.x * 256 + threadIdx.x;
  const float4* s = (const float4*)x + t * 2;
  float4 a = s[0], b = s[1];
  h8v o;
  o[0] = (_Float16)a.x; o[1] = (_Float16)a.y; o[2] = (_Float16)a.z; o[3] = (_Float16)a.w;
  o[4] = (_Float16)b.x; o[5] = (_Float16)b.y; o[6] = (_Float16)b.z; o[7] = (_Float16)b.w;
  ((h8v*)xh)[t] = o;
}

// ---- prepass 2: full dequant W -> f16 [OUT][IN], natural order ----
// w[k=2i] = (sext4(lo) - z) * s = s*(lo^8) + c,  c = -s*(8+z)
__global__ __launch_bounds__(256) void dequant_w_kernel(const int* __restrict__ wp,
                                                        const float* __restrict__ ws,
                                                        const int* __restrict__ wz,
                                                        _Float16* __restrict__ bh) {
  size_t tg = (size_t)blockIdx.x * 256 + threadIdx.x;
  int j   = (int)(tg & 127);   // 128 threads per row, 16 ints each
  int row = (int)(tg >> 7);
  int g = j >> 2;              // 32 weights per thread, group = 128
  float s = ws[(size_t)row * NGRP + g];
  float c = -s * (8.0f + (float)wz[(size_t)row * NGRP + g]);
  const int4* src = (const int4*)(wp + (size_t)row * 2048 + j * 16);
  _Float16* dst = bh + (size_t)row * 4096 + j * 32;
#pragma unroll
  for (int b = 0; b < 4; ++b) {
    int4 v = src[b];
    int q[4] = {v.x, v.y, v.z, v.w};
    h8v o;
#pragma unroll
    for (int i = 0; i < 4; ++i) {
      int lo = (q[i] & 15) ^ 8;
      int hi = ((q[i] >> 4) & 15) ^ 8;
      o[2 * i]     = (_Float16)(s * (float)lo + c);
      o[2 * i + 1] = (_Float16)(s * (float)hi + c);
    }
    ((h8v*)dst)[b] = o;
  }
}

// ---- GEMM: 256x256 tile, BK=64, 8 waves (2M x 4N), pipelined 8-phase ----
// LDS per buffer: A 32KB (2 K-half sections of 16KB) + B 32KB. 2 buffers = 128KB.
// byte(row,kchunk) = sec(kchunk>>2)*16384 + (row*4 + (kchunk&3)^((row>>1)&3))*16
__global__ __launch_bounds__(512, 2) void gemm_kernel(
    const _Float16* __restrict__ Ah,
    const _Float16* __restrict__ Bh,
    float* __restrict__ C) {
  __shared__ __align__(128) char smem[131072];

  const int bid = blockIdx.x;
  // XCD swizzle, bijective (688 = 8*86): each XCD owns 2 full m-rows of tiles
  const int swz = (bid & 7) * 86 + (bid >> 3);
  const int mt = swz / NTI;
  const int nt = swz - mt * NTI;
  const int m0 = mt * 256;
  const int n0 = nt * 256;

  const int tid  = threadIdx.x;
  const int lane = tid & 63;
  const int wid  = tid >> 6;
  const int wm   = wid >> 2;   // 0..1
  const int wn   = wid & 3;    // 0..3
  const int lrow = lane & 15;
  const int quad = lane >> 4;

  // staging: thread covers rows r0, r0+16 of the tile, one 16B kchunk each.
  // pre-swizzled global kchunk so linear gload_lds dest realizes the LDS swizzle.
  const int r0 = wid * 32 + (lane >> 2);             // 0..255 (j=0), +16 (j=1)
  const int kc = (lane & 3) ^ ((lane >> 3) & 3);     // slot ^ f(row), f = (row>>1)&3
  const size_t gA0 = (size_t)(m0 + r0) * K_IN + kc * 8;
  const size_t gB0 = (size_t)(n0 + r0) * K_IN + kc * 8;
  const int ldsl = wid * 2048;                       // + j*1024, wave-uniform

  // fragment read offsets (within a section): slot = quad ^ ((row>>1)&3)
  const int su   = quad ^ ((lrow >> 1) & 3);
  const int aoff = ((wm * 128 + lrow) * 4 + su) * 16;
  const int boff = 32768 + ((wn * 64 + lrow) * 4 + su) * 16;

  f4v acc[8][4];
#pragma unroll
  for (int i = 0; i < 8; ++i)
#pragma unroll
    for (int j = 0; j < 4; ++j) acc[i][j] = (f4v){0.f, 0.f, 0.f, 0.f};

  h8v af_a[4], af_b[4], bf_a[4], bf_b[4];

// stage both A and B halves of (tile KT, k-half KH) -> buffer NXT (4 loads)
#define STAGE4(NXT, KT, KH)                                                    \
  { const _Float16* gA_ = Ah + gA0 + (size_t)(KT) * 64 + (KH) * 32;            \
    const _Float16* gB_ = Bh + gB0 + (size_t)(KT) * 64 + (KH) * 32;            \
    char* lA_ = smem + (NXT) * 65536 + (KH) * 16384 + ldsl;                    \
    gload16(gA_, lA_);                                                         \
    gload16(gA_ + 16 * K_IN, lA_ + 1024);                                      \
    gload16(gB_, lA_ + 32768);                                                 \
    gload16(gB_ + 16 * K_IN, lA_ + 32768 + 1024); }

#define RD_AF(DST, BUF, SEC, MH)                                               \
  { const char* s_ = smem + (BUF) * 65536 + (SEC) * 16384;                     \
    _Pragma("unroll")                                                          \
    for (int i_ = 0; i_ < 4; ++i_)                                             \
      DST[i_] = *(const h8v*)(s_ + aoff + (MH) * 4096 + i_ * 1024); }

#define RD_BF(DST, BUF, SEC)                                                   \
  { const char* s_ = smem + (BUF) * 65536 + (SEC) * 16384;                     \
    _Pragma("unroll")                                                          \
    for (int i_ = 0; i_ < 4; ++i_)                                             \
      DST[i_] = *(const h8v*)(s_ + boff + i_ * 1024); }

#define MFMA16(AF, BF, MH)                                                     \
  { __builtin_amdgcn_s_setprio(1);                                             \
    _Pragma("unroll")                                                          \
    for (int mi_ = 0; mi_ < 4; ++mi_)                                          \
      _Pragma("unroll")                                                        \
      for (int nf_ = 0; nf_ < 4; ++nf_)                                        \
        acc[(MH) * 4 + mi_][nf_] = __builtin_amdgcn_mfma_f32_16x16x32_f16(     \
            AF[mi_], BF[nf_], acc[(MH) * 4 + mi_][nf_], 0, 0, 0);              \
    __builtin_amdgcn_s_setprio(0); }

  // prologue: tile 0 both halves -> buf0; vmcnt(4) retires h0 on all waves;
  // barrier publishes it; pre-read ph1's fragments.
  STAGE4(0, 0, 0);
  STAGE4(0, 0, 1);
  WAIT_VM4;
  BAR;
  RD_AF(af_a, 0, 0, 0);
  RD_BF(bf_a, 0, 0);

  // Stages: G1@ph1 (t+1 h0 -> buf1), G2@ph3 (t+1 h1), G3@ph5 (t+2 h0 -> buf0),
  // G4@ph7 (t+2 h1). Odd phases end [vmcnt(4); bar]: retire the group whose
  // section the NEXT phase reads, on ALL waves, before any wave's read.
  for (int t = 0; t < 64; t += 2) {
    const int t1 = t + 1;
    const int t2 = (t + 2 < 64) ? t + 2 : 63;  // tail: dummy restage, dead
    // ph1: MFMA buf0.s0 MH0; pre-read buf0.s0 MH1; retire prologue-h1
    RD_AF(af_b, 0, 0, 1); STAGE4(1, t1, 0); MFMA16(af_a, bf_a, 0); WAIT_VM4; BAR;
    // ph2: MFMA buf0.s0 MH1; pre-read buf0.s1 (af MH0 + bf)
    RD_AF(af_a, 0, 1, 0); RD_BF(bf_b, 0, 1); MFMA16(af_b, bf_a, 1); BAR;
    // ph3: MFMA buf0.s1 MH0; pre-read buf0.s1 MH1; retire G1
    RD_AF(af_b, 0, 1, 1); STAGE4(1, t1, 1); MFMA16(af_a, bf_b, 0); WAIT_VM4; BAR;
    // ph4: MFMA buf0.s1 MH1; pre-read buf1.s0 (af MH0 + bf)
    RD_AF(af_a, 1, 0, 0); RD_BF(bf_a, 1, 0); MFMA16(af_b, bf_b, 1); BAR;
    // ph5: MFMA buf1.s0 MH0; pre-read buf1.s0 MH1; retire G2
    RD_AF(af_b, 1, 0, 1); STAGE4(0, t2, 0); MFMA16(af_a, bf_a, 0); WAIT_VM4; BAR;
    // ph6: MFMA buf1.s0 MH1; pre-read buf1.s1 (af MH0 + bf)
    RD_AF(af_a, 1, 1, 0); RD_BF(bf_b, 1, 1); MFMA16(af_b, bf_a, 1); BAR;
    // ph7: MFMA buf1.s1 MH0; pre-read buf1.s1 MH1; retire G3
    RD_AF(af_b, 1, 1, 1); STAGE4(0, t2, 1); MFMA16(af_a, bf_b, 0); WAIT_VM4; BAR;
    // ph8: MFMA buf1.s1 MH1; pre-read buf0.s0 (af MH0 + bf) for next iter
    RD_AF(af_a, 0, 0, 0); RD_BF(bf_a, 0, 0); MFMA16(af_b, bf_b, 1); BAR;
  }

  // epilogue: C/D layout col = lane&15 (n), row = quad*4 + reg (m)
#pragma unroll
  for (int mf = 0; mf < 8; ++mf) {
#pragma unroll
    for (int rr = 0; rr < 4; ++rr) {
      int m = m0 + wm * 128 + mf * 16 + quad * 4 + rr;
      float* crow = C + (size_t)m * N_OUT + n0 + wn * 64 + lrow;
#pragma unroll
      for (int nf = 0; nf < 4; ++nf) crow[nf * 16] = acc[mf][nf][rr];
    }
  }
#undef MFMA16
#undef RD_BF
#undef RD_AF
#undef STAGE4
}

extern "C" void kernel_launch(void* const* d_in, const int* in_sizes, int n_in,
                              void* d_out, int out_size, void* d_ws, size_t ws_size,
                              hipStream_t stream) {
  const float* x   = (const float*)d_in[0];
  const int*   wp  = (const int*)d_in[1];
  const float* wsc = (const float*)d_in[2];
  const int*   wz  = (const int*)d_in[3];

  _Float16* Ah = (_Float16*)d_ws;
  _Float16* Bh = (_Float16*)((char*)d_ws + BH_OFF);

  cvt_x_kernel<<<(M_TOK * (size_t)K_IN) / (8 * 256), 256, 0, stream>>>(x, Ah);
  dequant_w_kernel<<<((size_t)N_OUT * 128) / 256, 256, 0, stream>>>(wp, wsc, wz, Bh);
  gemm_kernel<<<TILES, 512, 0, stream>>>(Ah, Bh, (float*)d_out);
}